// Round 13
// baseline (95.919 us; speedup 1.0000x reference)
//
#include <hip/hip_runtime.h>

#define NROWS 8192
#define DDIM  64
#define KNN   32
#define MAXIT 100
#define ROWS_PER_BLOCK 2

// alpha/beta arrive as 1-element arrays; robust to int32 or float32 encoding.
__device__ __forceinline__ float scalar_val(const void* p) {
    int iv = *(const int*)p;
    if (iv > -1000000 && iv < 1000000) return (float)iv;
    return *(const float*)p;
}

// 64-thread block (1 wave), 2 rows (one per half-wave). Same per-half-wave
// program as the R12 champion (quad-per-column distances, ballot Newton,
// merged zero+scatter stream). The ~39KB LDS pad caps residency at 4
// blocks/CU -> grid 4096 / resident 1024 = 4 GENERATIONS: a retiring
// block's store drain overlaps the next block's compute front.
__global__ __launch_bounds__(64) void school_fused_kernel(
    const float* __restrict__ Y,
    const float* __restrict__ semH,
    const float* __restrict__ orthoH,
    const int*   __restrict__ idx,
    const void*  alpha_p,
    const void*  beta_p,
    float* __restrict__ embs,   // N*D
    float* __restrict__ A,      // N*N
    float* __restrict__ Yout)   // N*D
{
    __shared__ int    col_s[ROWS_PER_BLOCK][KNN];
    __shared__ float  ad_s[ROWS_PER_BLOCK][KNN];
    __shared__ float2 cw_s[ROWS_PER_BLOCK][KNN];
    __shared__ char   occupancy_pad[39424];   // residency cap: 4 blocks/CU

    const int tid  = threadIdx.x;
    const int j    = tid & 31;      // lane within half-wave = neighbor slot
    const int r    = tid >> 5;      // row-within-block, 0..1 (half-wave id)
    const int row0 = blockIdx.x * ROWS_PER_BLOCK;
    const int row  = row0 + r;

    const float alpha = scalar_val(alpha_p);
    const float beta  = scalar_val(beta_p);

    // keep the pad allocated (condition can never be true at runtime)
    if (__float_as_int(alpha) == 0x7F123456) ((volatile char*)occupancy_pad)[0] = 1;

    // ---- Phase 0: neighbor ids -> LDS ----
    const int col = idx[row * 64 + 1 + j];       // idxa0 = idx[:, 1:33]
    col_s[r][j] = col;

    // ---- Phase 1: distances, quad-per-column (xor1/xor2 DPP reduces) ----
    const float4* Y4 = (const float4*)Y;
    const float4* O4 = (const float4*)orthoH;
    const int p = j & 3;            // quad lane
    const int Q = j >> 2;           // quad id 0..7

    float4 oy0 = Y4[(size_t)row * 16 + p +  0];
    float4 oy1 = Y4[(size_t)row * 16 + p +  4];
    float4 oy2 = Y4[(size_t)row * 16 + p +  8];
    float4 oy3 = Y4[(size_t)row * 16 + p + 12];
    float4 oo0 = O4[(size_t)row * 16 + p +  0];
    float4 oo1 = O4[(size_t)row * 16 + p +  4];
    float4 oo2 = O4[(size_t)row * 16 + p +  8];
    float4 oo3 = O4[(size_t)row * 16 + p + 12];

    #pragma unroll 2
    for (int b = 0; b < 4; ++b) {
        const int cidx = b * 8 + Q;
        const int c = col_s[r][cidx];
        float dY = 0.f, dO = 0.f;
        #define ACC_PH(ph, oy, oo)                                          \
        {                                                                   \
            float4 gY = Y4[(size_t)c * 16 + p + 4 * ph];                    \
            float4 gO = O4[(size_t)c * 16 + p + 4 * ph];                    \
            float ex = oy.x - gY.x, ey = oy.y - gY.y,                       \
                  ez = oy.z - gY.z, ew = oy.w - gY.w;                       \
            dY += ex * ex + ey * ey + ez * ez + ew * ew;                    \
            ex = oo.x - gO.x; ey = oo.y - gO.y;                             \
            ez = oo.z - gO.z; ew = oo.w - gO.w;                             \
            dO += ex * ex + ey * ey + ez * ez + ew * ew;                    \
        }
        ACC_PH(0, oy0, oo0)
        ACC_PH(1, oy1, oo1)
        ACC_PH(2, oy2, oo2)
        ACC_PH(3, oy3, oo3)
        #undef ACC_PH
        dY += __shfl_xor(dY, 1, 64);
        dY += __shfl_xor(dY, 2, 64);
        dO += __shfl_xor(dO, 1, 64);
        dO += __shfl_xor(dO, 2, 64);
        if (p == 0) {
            float dfv = sqrtf(dY + 1e-8f);          // dfi (from Y)
            float dxv = sqrtf(dO + 1e-8f);          // dxi (from ortho_H)
            ad_s[r][cidx] = -(dxv + beta * dfv) / (2.f * alpha);
        }
    }
    const float ad = ad_s[r][j];

    // ---- Phase 2: simplex projection (32 lanes = one row) ----
    float s = ad;
    #pragma unroll
    for (int mm = 1; mm <= 16; mm <<= 1) s += __shfl_xor(s, mm, 64);
    const float v0 = ad - s * (1.f / 32.f) + (1.f / 32.f);

    // Newton with tolerance exit; pos-count via ballot (no shfl tree).
    const unsigned long long halfmask = 0xFFFFFFFFull << (tid & 32);
    float lam = 0.f;
    #pragma unroll 1
    for (int it = 0; it < MAXIT; ++it) {
        float v1 = v0 - lam;
        bool pos = v1 > 0.f;
        float pp = pos ? v1 : 0.f;
        #pragma unroll
        for (int mm = 1; mm <= 16; mm <<= 1) pp += __shfl_xor(pp, mm, 64);
        float c = (float)__popcll(__ballot(pos ? 1 : 0) & halfmask);
        float step = (pp - 1.f) / fmaxf(c, 1.f);
        lam += step;
        if (__all(fabsf(step) <= 1e-6f ? 1 : 0)) break;
    }
    const float w = fmaxf(v0 - lam, 0.f);

    // ---- Phase 3: dedupe (np fancy-assignment: last j wins) ----
    bool dead = false;
    for (int jj = j + 1; jj < 32; ++jj)
        dead |= (col_s[r][jj] == col);
    cw_s[r][j] = make_float2(__int_as_float(col), dead ? 0.f : w);

    // ---- Phase 4: embs_hom[row] = sum_j w_j * semH[col_j]  (gathers issued
    //      BEFORE the store stream -> no vmcnt coupling) ----
    {
        float2 acc = make_float2(0.f, 0.f);
        const float2* H2 = (const float2*)semH;
        #pragma unroll 4
        for (int jj = 0; jj < KNN; ++jj) {
            float2 cw = cw_s[r][jj];
            int   c   = __float_as_int(cw.x);
            float wv  = cw.y;
            float2 h = H2[(size_t)c * 32 + j];
            acc.x += wv * h.x;
            acc.y += wv * h.y;
        }
        ((float2*)embs)[(size_t)row * 32 + j] = acc;
    }

    // ---- Phase 5: Y passthrough (2 rows = 64 float2) ----
    {
        const float2* Y2 = (const float2*)(Y + (size_t)row0 * DDIM);
        float2* O2 = (float2*)(Yout + (size_t)row0 * DDIM);
        O2[tid] = Y2[tid];
    }

    // ---- Phase 6: k-slot scan (ascending jj => ascending apply = last-wins)
    // Lane j owns float4 chunks i = 32*ss + j; col c -> owner (c>>2)&31,
    // ss = c>>7, pos = c&3.
    unsigned k0 = 0xFFFFFFFFu, k1 = 0xFFFFFFFFu, k2 = 0xFFFFFFFFu, k3 = 0xFFFFFFFFu;
    float f0 = 0.f, f1 = 0.f, f2 = 0.f, f3 = 0.f;
    int nhit = 0;
    #pragma unroll 1
    for (int jj = 0; jj < 32; ++jj) {
        float2 cw = cw_s[r][jj];
        int c = __float_as_int(cw.x);
        if (((c >> 2) & 31) == j) {
            unsigned key = ((unsigned)(c >> 7) << 2) | (unsigned)(c & 3);
            float wv = cw.y;
            k3 = (nhit == 3) ? key : k3;  f3 = (nhit == 3) ? wv : f3;
            k2 = (nhit == 2) ? key : k2;  f2 = (nhit == 2) ? wv : f2;
            k1 = (nhit == 1) ? key : k1;  f1 = (nhit == 1) ? wv : f1;
            k0 = (nhit == 0) ? key : k0;  f0 = (nhit == 0) ? wv : f0;
            nhit++;
        }
    }

    // ---- Phase 7: merged zero+scatter stream (unconditional 64 float4/lane)
    {
        float4* Arow4 = (float4*)(A + (size_t)row * NROWS);
        #pragma unroll 4
        for (int ss = 0; ss < 64; ++ss) {
            float4 v = make_float4(0.f, 0.f, 0.f, 0.f);
            #define APPLY_SLOT(kk, ff)                                   \
                if ((kk >> 2) == (unsigned)ss) {                         \
                    int p_ = (int)(kk & 3u);                             \
                    v.x = (p_ == 0) ? ff : v.x;                          \
                    v.y = (p_ == 1) ? ff : v.y;                          \
                    v.z = (p_ == 2) ? ff : v.z;                          \
                    v.w = (p_ == 3) ? ff : v.w;                          \
                }
            APPLY_SLOT(k0, f0)
            APPLY_SLOT(k1, f1)
            APPLY_SLOT(k2, f2)
            APPLY_SLOT(k3, f3)
            #undef APPLY_SLOT
            Arow4[(ss << 5) + j] = v;
        }
    }

    // ---- Phase 8: rare overflow (>4 cols on one lane): ordered dword fixups
    if (nhit > 4) {
        asm volatile("s_waitcnt vmcnt(0)" ::: "memory");
        int cnt = 0;
        for (int jj = 0; jj < 32; ++jj) {
            float2 cw = cw_s[r][jj];
            int c = __float_as_int(cw.x);
            if (((c >> 2) & 31) == j) {
                if (cnt >= 4) {
                    A[(size_t)row * NROWS + c] = cw.y;
                    asm volatile("s_waitcnt vmcnt(0)" ::: "memory");
                }
                cnt++;
            }
        }
    }
}

extern "C" void kernel_launch(void* const* d_in, const int* in_sizes, int n_in,
                              void* d_out, int out_size, void* d_ws, size_t ws_size,
                              hipStream_t stream) {
    const float* Y      = (const float*)d_in[0];
    const float* semH   = (const float*)d_in[1];
    const float* orthoH = (const float*)d_in[2];
    const int*   idx    = (const int*)d_in[3];
    const void*  alpha  = d_in[4];
    const void*  beta   = d_in[5];

    float* out  = (float*)d_out;
    float* embs = out;                                   // N*D
    float* A    = out + (size_t)NROWS * DDIM;            // N*N
    float* Yout = A + (size_t)NROWS * NROWS;             // N*D

    school_fused_kernel<<<NROWS / ROWS_PER_BLOCK, 64, 0, stream>>>(
        Y, semH, orthoH, idx, alpha, beta, embs, A, Yout);
}

// Round 14
// 65.734 us; speedup vs baseline: 1.4592x; 1.4592x over previous
//
#include <hip/hip_runtime.h>

#define NROWS 8192
#define DDIM  64
#define KNN   32
#define MAXIT 100

// alpha/beta arrive as 1-element arrays; robust to int32 or float32 encoding.
__device__ __forceinline__ float scalar_val(const void* p) {
    int iv = *(const int*)p;
    if (iv > -1000000 && iv < 1000000) return (float)iv;
    return *(const float*)p;
}

// One block = 8 rows, half-wave (32 lanes) per row. R12 champion front
// (quad-per-column distances, ballot Newton) restructured for in-wave
// store/compute overlap:
//   [all loads issued & distance-consumed] -> [zero-stream: ~63 idx-only
//   stores] -> [Newton/dedupe/scan: pure VALU/DS, hides under HBM drain]
//   -> [embs consume (loads older than stores: FIFO vmcnt, no coupling)]
//   -> [merged hit-chunk stores + rare overflow]
__global__ __launch_bounds__(256, 4) void school_fused_kernel(
    const float* __restrict__ Y,
    const float* __restrict__ semH,
    const float* __restrict__ orthoH,
    const int*   __restrict__ idx,
    const void*  alpha_p,
    const void*  beta_p,
    float* __restrict__ embs,   // N*D
    float* __restrict__ A,      // N*N
    float* __restrict__ Yout)   // N*D
{
    __shared__ int    col_s[8][KNN];
    __shared__ float  ad_s[8][KNN];
    __shared__ float2 cw_s[8][KNN];   // packed {bitcast(col), w_deduped}

    const int tid  = threadIdx.x;
    const int j    = tid & 31;      // lane within half-wave = neighbor slot
    const int r    = tid >> 5;      // row-within-block, 0..7 (half-wave id)
    const int row0 = blockIdx.x * 8;
    const int row  = row0 + r;

    const float alpha = scalar_val(alpha_p);
    const float beta  = scalar_val(beta_p);

    // ---- Phase 0: neighbor ids -> LDS; per-lane chunk hitmask ----
    const int col = idx[row * 64 + 1 + j];       // idxa0 = idx[:, 1:33]
    col_s[r][j] = col;

    // Lane j owns float4 chunks i = 32*ss + j; col c -> owner (c>>2)&31,
    // ss = c>>7. Pure function of idx (no distances needed).
    unsigned long long hitmask = 0ull;
    #pragma unroll 1
    for (int jj = 0; jj < 32; ++jj) {
        int c = col_s[r][jj];
        if (((c >> 2) & 31) == j) hitmask |= 1ull << (c >> 7);
    }

    // ---- Phase 1: distances, quad-per-column (xor1/xor2 DPP reduces) ----
    const float4* Y4 = (const float4*)Y;
    const float4* O4 = (const float4*)orthoH;
    const int p = j & 3;            // quad lane
    const int Q = j >> 2;           // quad id 0..7

    float4 oy0 = Y4[(size_t)row * 16 + p +  0];
    float4 oy1 = Y4[(size_t)row * 16 + p +  4];
    float4 oy2 = Y4[(size_t)row * 16 + p +  8];
    float4 oy3 = Y4[(size_t)row * 16 + p + 12];
    float4 oo0 = O4[(size_t)row * 16 + p +  0];
    float4 oo1 = O4[(size_t)row * 16 + p +  4];
    float4 oo2 = O4[(size_t)row * 16 + p +  8];
    float4 oo3 = O4[(size_t)row * 16 + p + 12];

    #pragma unroll 2
    for (int b = 0; b < 4; ++b) {
        const int cidx = b * 8 + Q;
        const int c = col_s[r][cidx];
        float dY = 0.f, dO = 0.f;
        #define ACC_PH(ph, oy, oo)                                          \
        {                                                                   \
            float4 gY = Y4[(size_t)c * 16 + p + 4 * ph];                    \
            float4 gO = O4[(size_t)c * 16 + p + 4 * ph];                    \
            float ex = oy.x - gY.x, ey = oy.y - gY.y,                       \
                  ez = oy.z - gY.z, ew = oy.w - gY.w;                       \
            dY += ex * ex + ey * ey + ez * ez + ew * ew;                    \
            ex = oo.x - gO.x; ey = oo.y - gO.y;                             \
            ez = oo.z - gO.z; ew = oo.w - gO.w;                             \
            dO += ex * ex + ey * ey + ez * ez + ew * ew;                    \
        }
        ACC_PH(0, oy0, oo0)
        ACC_PH(1, oy1, oo1)
        ACC_PH(2, oy2, oo2)
        ACC_PH(3, oy3, oo3)
        #undef ACC_PH
        dY += __shfl_xor(dY, 1, 64);
        dY += __shfl_xor(dY, 2, 64);
        dO += __shfl_xor(dO, 1, 64);
        dO += __shfl_xor(dO, 2, 64);
        if (p == 0) {
            float dfv = sqrtf(dY + 1e-8f);          // dfi (from Y)
            float dxv = sqrtf(dO + 1e-8f);          // dxi (from ortho_H)
            ad_s[r][cidx] = -(dxv + beta * dfv) / (2.f * alpha);
        }
    }
    const float ad = ad_s[r][j];

    // ---- Phase 2: Y passthrough (load consumed now, before bulk stores) ----
    {
        const float2* Y2 = (const float2*)(Y + (size_t)row0 * DDIM);
        float2* O2 = (float2*)(Yout + (size_t)row0 * DDIM);
        O2[tid] = Y2[tid];
    }

    // ---- Phase 3: embs gather ISSUE (addresses need col only; data held in
    //      regs across the store stream; loads are OLDER than the stores so
    //      FIFO vmcnt retires them first -> consume never waits on drain) ----
    float2 h_arr[32];
    {
        const float2* H2 = (const float2*)semH;
        #pragma unroll
        for (int jj = 0; jj < KNN; ++jj) {
            int c = col_s[r][jj];
            h_arr[jj] = H2[(size_t)c * 32 + j];
        }
    }

    __builtin_amdgcn_sched_barrier(0);

    // ---- Phase 4: ZERO-STREAM for non-hit chunks (~63 pure stores/lane) ----
    {
        const float4 z4 = make_float4(0.f, 0.f, 0.f, 0.f);
        float4* Arow4 = (float4*)(A + (size_t)row * NROWS);
        #pragma unroll 8
        for (int ss = 0; ss < 64; ++ss) {
            if (!((hitmask >> ss) & 1ull))
                Arow4[(ss << 5) + j] = z4;
        }
    }

    __builtin_amdgcn_sched_barrier(0);

    // ---- Phase 5: Newton (pure VALU/DS -> runs while stores drain) ----
    float s = ad;
    #pragma unroll
    for (int mm = 1; mm <= 16; mm <<= 1) s += __shfl_xor(s, mm, 64);
    const float v0 = ad - s * (1.f / 32.f) + (1.f / 32.f);

    const unsigned long long halfmask = 0xFFFFFFFFull << (tid & 32);
    float lam = 0.f;
    #pragma unroll 1
    for (int it = 0; it < MAXIT; ++it) {
        float v1 = v0 - lam;
        bool pos = v1 > 0.f;
        float pp = pos ? v1 : 0.f;
        #pragma unroll
        for (int mm = 1; mm <= 16; mm <<= 1) pp += __shfl_xor(pp, mm, 64);
        float c = (float)__popcll(__ballot(pos ? 1 : 0) & halfmask);
        float step = (pp - 1.f) / fmaxf(c, 1.f);
        lam += step;
        if (__all(fabsf(step) <= 1e-6f ? 1 : 0)) break;
    }
    const float w = fmaxf(v0 - lam, 0.f);

    // ---- Phase 6: dedupe (np fancy-assignment: last j wins); still hidden ----
    bool dead = false;
    for (int jj = j + 1; jj < 32; ++jj)
        dead |= (col_s[r][jj] == col);
    cw_s[r][j] = make_float2(__int_as_float(col), dead ? 0.f : w);

    // ---- Phase 7: k-slot scan (ascending jj = np last-wins); hidden ----
    unsigned k0 = 0xFFFFFFFFu, k1 = 0xFFFFFFFFu, k2 = 0xFFFFFFFFu, k3 = 0xFFFFFFFFu;
    float f0 = 0.f, f1 = 0.f, f2 = 0.f, f3 = 0.f;
    int nhit = 0;
    #pragma unroll 1
    for (int jj = 0; jj < 32; ++jj) {
        float2 cw = cw_s[r][jj];
        int c = __float_as_int(cw.x);
        if (((c >> 2) & 31) == j) {
            unsigned key = ((unsigned)(c >> 7) << 2) | (unsigned)(c & 3);
            float wv = cw.y;
            k3 = (nhit == 3) ? key : k3;  f3 = (nhit == 3) ? wv : f3;
            k2 = (nhit == 2) ? key : k2;  f2 = (nhit == 2) ? wv : f2;
            k1 = (nhit == 1) ? key : k1;  f1 = (nhit == 1) ? wv : f1;
            k0 = (nhit == 0) ? key : k0;  f0 = (nhit == 0) ? wv : f0;
            nhit++;
        }
    }

    // ---- Phase 8: embs consume + store (h_arr loads already retired) ----
    {
        float2 acc = make_float2(0.f, 0.f);
        #pragma unroll
        for (int jj = 0; jj < KNN; ++jj) {
            float wv = cw_s[r][jj].y;
            acc.x += wv * h_arr[jj].x;
            acc.y += wv * h_arr[jj].y;
        }
        ((float2*)embs)[(size_t)row * 32 + j] = acc;
    }

    // ---- Phase 9: merged HIT-chunk stores (E[popcount]=1 per lane) ----
    {
        float4* Arow4 = (float4*)(A + (size_t)row * NROWS);
        unsigned long long mrem = hitmask;
        while (mrem) {
            int ss = __ffsll(mrem) - 1;
            mrem &= mrem - 1;
            float4 v = make_float4(0.f, 0.f, 0.f, 0.f);
            #define APPLY_SLOT(kk, ff)                                   \
                if ((int)(kk >> 2) == ss) {                              \
                    int p_ = (int)(kk & 3u);                             \
                    v.x = (p_ == 0) ? ff : v.x;                          \
                    v.y = (p_ == 1) ? ff : v.y;                          \
                    v.z = (p_ == 2) ? ff : v.z;                          \
                    v.w = (p_ == 3) ? ff : v.w;                          \
                }
            APPLY_SLOT(k0, f0)
            APPLY_SLOT(k1, f1)
            APPLY_SLOT(k2, f2)
            APPLY_SLOT(k3, f3)
            #undef APPLY_SLOT
            Arow4[(ss << 5) + j] = v;
        }
    }

    // ---- Phase 10: rare overflow (>4 cols on one lane): ordered fixups ----
    if (nhit > 4) {
        asm volatile("s_waitcnt vmcnt(0)" ::: "memory");
        int cnt = 0;
        for (int jj = 0; jj < 32; ++jj) {
            float2 cw = cw_s[r][jj];
            int c = __float_as_int(cw.x);
            if (((c >> 2) & 31) == j) {
                if (cnt >= 4) {
                    A[(size_t)row * NROWS + c] = cw.y;
                    asm volatile("s_waitcnt vmcnt(0)" ::: "memory");
                }
                cnt++;
            }
        }
    }
}

extern "C" void kernel_launch(void* const* d_in, const int* in_sizes, int n_in,
                              void* d_out, int out_size, void* d_ws, size_t ws_size,
                              hipStream_t stream) {
    const float* Y      = (const float*)d_in[0];
    const float* semH   = (const float*)d_in[1];
    const float* orthoH = (const float*)d_in[2];
    const int*   idx    = (const int*)d_in[3];
    const void*  alpha  = d_in[4];
    const void*  beta   = d_in[5];

    float* out  = (float*)d_out;
    float* embs = out;                                   // N*D
    float* A    = out + (size_t)NROWS * DDIM;            // N*N
    float* Yout = A + (size_t)NROWS * NROWS;             // N*D

    school_fused_kernel<<<NROWS / 8, 256, 0, stream>>>(
        Y, semH, orthoH, idx, alpha, beta, embs, A, Yout);
}

// Round 15
// 57.502 us; speedup vs baseline: 1.6681x; 1.1432x over previous
//
#include <hip/hip_runtime.h>

#define NROWS 8192
#define DDIM  64
#define KNN   32
#define MAXIT 100

// alpha/beta arrive as 1-element arrays; robust to int32 or float32 encoding.
__device__ __forceinline__ float scalar_val(const void* p) {
    int iv = *(const int*)p;
    if (iv > -1000000 && iv < 1000000) return (float)iv;
    return *(const float*)p;
}

// One block = 8 rows, half-wave (32 lanes) per row. R12 champion structure;
// this round replaces the two serial scans (32-iter k-slot scan, 31-iter
// dedupe) with a ballot-transpose: 32 unrolled ballots give each lane the
// mask of neighbor-slots it owns (E[popcount]=1); slot-fill walks set bits
// and collapses duplicate cols in place (same col -> same owner, same key).
// Rare overflow (>4 distinct keys on a lane) falls back to the old dedupe.
__global__ __launch_bounds__(256, 4) void school_fused_kernel(
    const float* __restrict__ Y,
    const float* __restrict__ semH,
    const float* __restrict__ orthoH,
    const int*   __restrict__ idx,
    const void*  alpha_p,
    const void*  beta_p,
    float* __restrict__ embs,   // N*D
    float* __restrict__ A,      // N*N
    float* __restrict__ Yout)   // N*D
{
    __shared__ int    col_s[8][KNN];
    __shared__ float  ad_s[8][KNN];
    __shared__ float2 cw_s[8][KNN];   // packed {bitcast(col), w}

    const int tid  = threadIdx.x;
    const int j    = tid & 31;      // lane within half-wave = neighbor slot
    const int r    = tid >> 5;      // row-within-block, 0..7 (half-wave id)
    const int row0 = blockIdx.x * 8;
    const int row  = row0 + r;

    const float alpha = scalar_val(alpha_p);
    const float beta  = scalar_val(beta_p);

    // ---- Phase 0: neighbor ids -> LDS ----
    const int col = idx[row * 64 + 1 + j];       // idxa0 = idx[:, 1:33]
    col_s[r][j] = col;

    // ---- Phase 1: distances, quad-per-column (xor1/xor2 DPP reduces) ----
    const float4* Y4 = (const float4*)Y;
    const float4* O4 = (const float4*)orthoH;
    const int p = j & 3;            // quad lane
    const int Q = j >> 2;           // quad id 0..7

    float4 oy0 = Y4[(size_t)row * 16 + p +  0];
    float4 oy1 = Y4[(size_t)row * 16 + p +  4];
    float4 oy2 = Y4[(size_t)row * 16 + p +  8];
    float4 oy3 = Y4[(size_t)row * 16 + p + 12];
    float4 oo0 = O4[(size_t)row * 16 + p +  0];
    float4 oo1 = O4[(size_t)row * 16 + p +  4];
    float4 oo2 = O4[(size_t)row * 16 + p +  8];
    float4 oo3 = O4[(size_t)row * 16 + p + 12];

    #pragma unroll 2
    for (int b = 0; b < 4; ++b) {
        const int cidx = b * 8 + Q;
        const int c = col_s[r][cidx];
        float dY = 0.f, dO = 0.f;
        #define ACC_PH(ph, oy, oo)                                          \
        {                                                                   \
            float4 gY = Y4[(size_t)c * 16 + p + 4 * ph];                    \
            float4 gO = O4[(size_t)c * 16 + p + 4 * ph];                    \
            float ex = oy.x - gY.x, ey = oy.y - gY.y,                       \
                  ez = oy.z - gY.z, ew = oy.w - gY.w;                       \
            dY += ex * ex + ey * ey + ez * ez + ew * ew;                    \
            ex = oo.x - gO.x; ey = oo.y - gO.y;                             \
            ez = oo.z - gO.z; ew = oo.w - gO.w;                             \
            dO += ex * ex + ey * ey + ez * ez + ew * ew;                    \
        }
        ACC_PH(0, oy0, oo0)
        ACC_PH(1, oy1, oo1)
        ACC_PH(2, oy2, oo2)
        ACC_PH(3, oy3, oo3)
        #undef ACC_PH
        dY += __shfl_xor(dY, 1, 64);
        dY += __shfl_xor(dY, 2, 64);
        dO += __shfl_xor(dO, 1, 64);
        dO += __shfl_xor(dO, 2, 64);
        if (p == 0) {
            float dfv = sqrtf(dY + 1e-8f);          // dfi (from Y)
            float dxv = sqrtf(dO + 1e-8f);          // dxi (from ortho_H)
            ad_s[r][cidx] = -(dxv + beta * dfv) / (2.f * alpha);
        }
    }
    const float ad = ad_s[r][j];

    // ---- Phase 2: simplex projection (32 lanes = one row) ----
    float s = ad;
    #pragma unroll
    for (int mm = 1; mm <= 16; mm <<= 1) s += __shfl_xor(s, mm, 64);
    const float v0 = ad - s * (1.f / 32.f) + (1.f / 32.f);

    const unsigned long long halfsh = (unsigned long long)(tid & 32);
    const unsigned long long halfmask = 0xFFFFFFFFull << halfsh;
    float lam = 0.f;
    #pragma unroll 1
    for (int it = 0; it < MAXIT; ++it) {
        float v1 = v0 - lam;
        bool pos = v1 > 0.f;
        float pp = pos ? v1 : 0.f;
        #pragma unroll
        for (int mm = 1; mm <= 16; mm <<= 1) pp += __shfl_xor(pp, mm, 64);
        float c = (float)__popcll(__ballot(pos ? 1 : 0) & halfmask);
        float step = (pp - 1.f) / fmaxf(c, 1.f);
        lam += step;
        if (__all(fabsf(step) <= 1e-6f ? 1 : 0)) break;
    }
    const float w = fmaxf(v0 - lam, 0.f);

    // ---- Phase 3: publish raw (col, w); dedupe handled by owners below ----
    cw_s[r][j] = make_float2(__int_as_float(col), w);

    // ---- Phase 4: ballot-transpose -> mymask (which jj are mine) ----
    // Owner of col c is lane (c>>2)&31 of the half-wave.
    const int myowner = (col >> 2) & 31;
    unsigned mymask = 0u;
    #pragma unroll
    for (int o = 0; o < 32; ++o) {
        unsigned long long b = __ballot(myowner == o ? 1 : 0);
        if (j == o) mymask = (unsigned)(b >> halfsh);
    }

    // ---- Phase 5: slot-fill over my hits (ascending jj = np last-wins).
    // Duplicate col => same owner, same key: collapse in place, zero the
    // earlier entry's w in cw_s (for embs). key=(ss<<2)|pos, ss=c>>7, pos=c&3.
    unsigned k0 = ~0u, k1 = ~0u, k2 = ~0u, k3 = ~0u;
    float f0 = 0.f, f1 = 0.f, f2 = 0.f, f3 = 0.f;
    int j0 = 0, j1 = 0, j2 = 0, j3 = 0;
    int nhit = 0;
    unsigned ovmask = 0u;
    {
        unsigned mrem = mymask;
        while (mrem) {
            int jj = __ffs(mrem) - 1;
            mrem &= mrem - 1;
            float2 cw = cw_s[r][jj];
            int c = __float_as_int(cw.x);
            unsigned key = ((unsigned)(c >> 7) << 2) | (unsigned)(c & 3);
            float wv = cw.y;
            if      (nhit > 0 && key == k0) { cw_s[r][j0].y = 0.f; f0 = wv; j0 = jj; }
            else if (nhit > 1 && key == k1) { cw_s[r][j1].y = 0.f; f1 = wv; j1 = jj; }
            else if (nhit > 2 && key == k2) { cw_s[r][j2].y = 0.f; f2 = wv; j2 = jj; }
            else if (nhit > 3 && key == k3) { cw_s[r][j3].y = 0.f; f3 = wv; j3 = jj; }
            else if (nhit == 0) { k0 = key; f0 = wv; j0 = jj; nhit = 1; }
            else if (nhit == 1) { k1 = key; f1 = wv; j1 = jj; nhit = 2; }
            else if (nhit == 2) { k2 = key; f2 = wv; j2 = jj; nhit = 3; }
            else if (nhit == 3) { k3 = key; f3 = wv; j3 = jj; nhit = 4; }
            else { ovmask |= 1u << jj; }
        }
    }

    // ---- Phase 6: overflow rows fall back to exact full dedupe (rare).
    // Slots stay valid: any dup among slots was already collapsed exactly.
    {
        unsigned long long ovb = __ballot(ovmask != 0u ? 1 : 0);
        if (((ovb >> halfsh) & 0xFFFFFFFFull) != 0ull) {
            bool dead = false;
            for (int jj2 = j + 1; jj2 < 32; ++jj2)
                dead |= (col_s[r][jj2] == col);
            cw_s[r][j] = make_float2(__int_as_float(col), dead ? 0.f : w);
        }
    }

    // ---- Phase 7: embs_hom[row] = sum_j w_j * semH[col_j] (pre-stream) ----
    {
        float2 acc = make_float2(0.f, 0.f);
        const float2* H2 = (const float2*)semH;
        #pragma unroll 4
        for (int jj = 0; jj < KNN; ++jj) {
            float2 cw = cw_s[r][jj];
            int   c   = __float_as_int(cw.x);
            float wv  = cw.y;
            float2 h = H2[(size_t)c * 32 + j];
            acc.x += wv * h.x;
            acc.y += wv * h.y;
        }
        ((float2*)embs)[(size_t)row * 32 + j] = acc;
    }

    // ---- Phase 8: Y passthrough ----
    {
        const float2* Y2 = (const float2*)(Y + (size_t)row0 * DDIM);
        float2* O2 = (float2*)(Yout + (size_t)row0 * DDIM);
        O2[tid] = Y2[tid];
    }

    // ---- Phase 9: merged zero+scatter stream (unconditional 64 float4/lane)
    {
        float4* Arow4 = (float4*)(A + (size_t)row * NROWS);
        #pragma unroll 4
        for (int ss = 0; ss < 64; ++ss) {
            float4 v = make_float4(0.f, 0.f, 0.f, 0.f);
            #define APPLY_SLOT(kk, ff)                                   \
                if ((kk >> 2) == (unsigned)ss) {                         \
                    int p_ = (int)(kk & 3u);                             \
                    v.x = (p_ == 0) ? ff : v.x;                          \
                    v.y = (p_ == 1) ? ff : v.y;                          \
                    v.z = (p_ == 2) ? ff : v.z;                          \
                    v.w = (p_ == 3) ? ff : v.w;                          \
                }
            APPLY_SLOT(k0, f0)
            APPLY_SLOT(k1, f1)
            APPLY_SLOT(k2, f2)
            APPLY_SLOT(k3, f3)
            #undef APPLY_SLOT
            Arow4[(ss << 5) + j] = v;
        }
    }

    // ---- Phase 10: overflow fixups (>4 distinct keys on a lane): ordered
    //      dword writes, ascending jj = np last-wins; values from corrected
    //      cw_s (dead entries write 0 then survivor overwrites).
    if (ovmask) {
        asm volatile("s_waitcnt vmcnt(0)" ::: "memory");
        unsigned m = ovmask;
        while (m) {
            int jj = __ffs(m) - 1;
            m &= m - 1;
            int c = col_s[r][jj];
            A[(size_t)row * NROWS + c] = cw_s[r][jj].y;
            asm volatile("s_waitcnt vmcnt(0)" ::: "memory");
        }
    }
}

extern "C" void kernel_launch(void* const* d_in, const int* in_sizes, int n_in,
                              void* d_out, int out_size, void* d_ws, size_t ws_size,
                              hipStream_t stream) {
    const float* Y      = (const float*)d_in[0];
    const float* semH   = (const float*)d_in[1];
    const float* orthoH = (const float*)d_in[2];
    const int*   idx    = (const int*)d_in[3];
    const void*  alpha  = d_in[4];
    const void*  beta   = d_in[5];

    float* out  = (float*)d_out;
    float* embs = out;                                   // N*D
    float* A    = out + (size_t)NROWS * DDIM;            // N*N
    float* Yout = A + (size_t)NROWS * NROWS;             // N*D

    school_fused_kernel<<<NROWS / 8, 256, 0, stream>>>(
        Y, semH, orthoH, idx, alpha, beta, embs, A, Yout);
}

// Round 16
// 56.814 us; speedup vs baseline: 1.6883x; 1.0121x over previous
//
#include <hip/hip_runtime.h>

#define NROWS 8192
#define DDIM  64
#define KNN   32
#define MAXIT 100

// alpha/beta arrive as 1-element arrays; robust to int32 or float32 encoding.
__device__ __forceinline__ float scalar_val(const void* p) {
    int iv = *(const int*)p;
    if (iv > -1000000 && iv < 1000000) return (float)iv;
    return *(const float*)p;
}

// One block = 8 rows, half-wave (32 lanes) per row. R15 champion structure.
// This round: cut the front's latency chains --
//  - distance gather addresses come from __shfl (register transpose), not an
//    LDS round-trip (col was written+read through LDS before)
//  - b-loop fully unrolled: all 32 gather loads in flight
//  - embs gather loop fully unrolled
__global__ __launch_bounds__(256, 4) void school_fused_kernel(
    const float* __restrict__ Y,
    const float* __restrict__ semH,
    const float* __restrict__ orthoH,
    const int*   __restrict__ idx,
    const void*  alpha_p,
    const void*  beta_p,
    float* __restrict__ embs,   // N*D
    float* __restrict__ A,      // N*N
    float* __restrict__ Yout)   // N*D
{
    __shared__ int    col_s[8][KNN];
    __shared__ float  ad_s[8][KNN];
    __shared__ float2 cw_s[8][KNN];   // packed {bitcast(col), w}

    const int tid  = threadIdx.x;
    const int j    = tid & 31;      // lane within half-wave = neighbor slot
    const int r    = tid >> 5;      // row-within-block, 0..7 (half-wave id)
    const int row0 = blockIdx.x * 8;
    const int row  = row0 + r;

    const float alpha = scalar_val(alpha_p);
    const float beta  = scalar_val(beta_p);

    // ---- Phase 0: neighbor ids; LDS copy kept for later phases ----
    const int col = idx[row * 64 + 1 + j];       // idxa0 = idx[:, 1:33]
    col_s[r][j] = col;

    // ---- Phase 1: distances, quad-per-column; cols via register shfl ----
    const float4* Y4 = (const float4*)Y;
    const float4* O4 = (const float4*)orthoH;
    const int p = j & 3;            // quad lane
    const int Q = j >> 2;           // quad id 0..7
    const int hbase = tid & 32;     // half-wave base within this wave

    // all 4 column ids for this quad, via cross-lane reg transpose (no LDS)
    const int c0 = __shfl(col, hbase | (0 * 8 + Q), 64);
    const int c1 = __shfl(col, hbase | (1 * 8 + Q), 64);
    const int c2 = __shfl(col, hbase | (2 * 8 + Q), 64);
    const int c3 = __shfl(col, hbase | (3 * 8 + Q), 64);

    float4 oy0 = Y4[(size_t)row * 16 + p +  0];
    float4 oy1 = Y4[(size_t)row * 16 + p +  4];
    float4 oy2 = Y4[(size_t)row * 16 + p +  8];
    float4 oy3 = Y4[(size_t)row * 16 + p + 12];
    float4 oo0 = O4[(size_t)row * 16 + p +  0];
    float4 oo1 = O4[(size_t)row * 16 + p +  4];
    float4 oo2 = O4[(size_t)row * 16 + p +  8];
    float4 oo3 = O4[(size_t)row * 16 + p + 12];

    const int cq[4] = {c0, c1, c2, c3};
    #pragma unroll
    for (int b = 0; b < 4; ++b) {
        const int cidx = b * 8 + Q;
        const int c = cq[b];
        float dY = 0.f, dO = 0.f;
        #define ACC_PH(ph, oy, oo)                                          \
        {                                                                   \
            float4 gY = Y4[(size_t)c * 16 + p + 4 * ph];                    \
            float4 gO = O4[(size_t)c * 16 + p + 4 * ph];                    \
            float ex = oy.x - gY.x, ey = oy.y - gY.y,                       \
                  ez = oy.z - gY.z, ew = oy.w - gY.w;                       \
            dY += ex * ex + ey * ey + ez * ez + ew * ew;                    \
            ex = oo.x - gO.x; ey = oo.y - gO.y;                             \
            ez = oo.z - gO.z; ew = oo.w - gO.w;                             \
            dO += ex * ex + ey * ey + ez * ez + ew * ew;                    \
        }
        ACC_PH(0, oy0, oo0)
        ACC_PH(1, oy1, oo1)
        ACC_PH(2, oy2, oo2)
        ACC_PH(3, oy3, oo3)
        #undef ACC_PH
        dY += __shfl_xor(dY, 1, 64);
        dY += __shfl_xor(dY, 2, 64);
        dO += __shfl_xor(dO, 1, 64);
        dO += __shfl_xor(dO, 2, 64);
        if (p == 0) {
            float dfv = sqrtf(dY + 1e-8f);          // dfi (from Y)
            float dxv = sqrtf(dO + 1e-8f);          // dxi (from ortho_H)
            ad_s[r][cidx] = -(dxv + beta * dfv) / (2.f * alpha);
        }
    }
    const float ad = ad_s[r][j];

    // ---- Phase 2: simplex projection (32 lanes = one row) ----
    float s = ad;
    #pragma unroll
    for (int mm = 1; mm <= 16; mm <<= 1) s += __shfl_xor(s, mm, 64);
    const float v0 = ad - s * (1.f / 32.f) + (1.f / 32.f);

    const unsigned long long halfsh = (unsigned long long)(tid & 32);
    const unsigned long long halfmask = 0xFFFFFFFFull << halfsh;
    float lam = 0.f;
    #pragma unroll 1
    for (int it = 0; it < MAXIT; ++it) {
        float v1 = v0 - lam;
        bool pos = v1 > 0.f;
        float pp = pos ? v1 : 0.f;
        #pragma unroll
        for (int mm = 1; mm <= 16; mm <<= 1) pp += __shfl_xor(pp, mm, 64);
        float c = (float)__popcll(__ballot(pos ? 1 : 0) & halfmask);
        float step = (pp - 1.f) / fmaxf(c, 1.f);
        lam += step;
        if (__all(fabsf(step) <= 1e-6f ? 1 : 0)) break;
    }
    const float w = fmaxf(v0 - lam, 0.f);

    // ---- Phase 3: publish raw (col, w); dedupe handled by owners below ----
    cw_s[r][j] = make_float2(__int_as_float(col), w);

    // ---- Phase 4: ballot-transpose -> mymask (which jj are mine) ----
    const int myowner = (col >> 2) & 31;
    unsigned mymask = 0u;
    #pragma unroll
    for (int o = 0; o < 32; ++o) {
        unsigned long long b = __ballot(myowner == o ? 1 : 0);
        if (j == o) mymask = (unsigned)(b >> halfsh);
    }

    // ---- Phase 5: slot-fill over my hits (ascending jj = np last-wins).
    // Duplicate col => same owner, same key: collapse in place, zero the
    // earlier entry's w in cw_s (for embs). key=(ss<<2)|pos, ss=c>>7, pos=c&3.
    unsigned k0 = ~0u, k1 = ~0u, k2 = ~0u, k3 = ~0u;
    float f0 = 0.f, f1 = 0.f, f2 = 0.f, f3 = 0.f;
    int j0 = 0, j1 = 0, j2 = 0, j3 = 0;
    int nhit = 0;
    unsigned ovmask = 0u;
    {
        unsigned mrem = mymask;
        while (mrem) {
            int jj = __ffs(mrem) - 1;
            mrem &= mrem - 1;
            float2 cw = cw_s[r][jj];
            int c = __float_as_int(cw.x);
            unsigned key = ((unsigned)(c >> 7) << 2) | (unsigned)(c & 3);
            float wv = cw.y;
            if      (nhit > 0 && key == k0) { cw_s[r][j0].y = 0.f; f0 = wv; j0 = jj; }
            else if (nhit > 1 && key == k1) { cw_s[r][j1].y = 0.f; f1 = wv; j1 = jj; }
            else if (nhit > 2 && key == k2) { cw_s[r][j2].y = 0.f; f2 = wv; j2 = jj; }
            else if (nhit > 3 && key == k3) { cw_s[r][j3].y = 0.f; f3 = wv; j3 = jj; }
            else if (nhit == 0) { k0 = key; f0 = wv; j0 = jj; nhit = 1; }
            else if (nhit == 1) { k1 = key; f1 = wv; j1 = jj; nhit = 2; }
            else if (nhit == 2) { k2 = key; f2 = wv; j2 = jj; nhit = 3; }
            else if (nhit == 3) { k3 = key; f3 = wv; j3 = jj; nhit = 4; }
            else { ovmask |= 1u << jj; }
        }
    }

    // ---- Phase 6: overflow rows fall back to exact full dedupe (rare) ----
    {
        unsigned long long ovb = __ballot(ovmask != 0u ? 1 : 0);
        if (((ovb >> halfsh) & 0xFFFFFFFFull) != 0ull) {
            bool dead = false;
            for (int jj2 = j + 1; jj2 < 32; ++jj2)
                dead |= (col_s[r][jj2] == col);
            cw_s[r][j] = make_float2(__int_as_float(col), dead ? 0.f : w);
        }
    }

    // ---- Phase 7: embs_hom[row] = sum_j w_j * semH[col_j] (pre-stream) ----
    {
        float2 acc = make_float2(0.f, 0.f);
        const float2* H2 = (const float2*)semH;
        #pragma unroll
        for (int jj = 0; jj < KNN; ++jj) {
            float2 cw = cw_s[r][jj];
            int   c   = __float_as_int(cw.x);
            float wv  = cw.y;
            float2 h = H2[(size_t)c * 32 + j];
            acc.x += wv * h.x;
            acc.y += wv * h.y;
        }
        ((float2*)embs)[(size_t)row * 32 + j] = acc;
    }

    // ---- Phase 8: Y passthrough ----
    {
        const float2* Y2 = (const float2*)(Y + (size_t)row0 * DDIM);
        float2* O2 = (float2*)(Yout + (size_t)row0 * DDIM);
        O2[tid] = Y2[tid];
    }

    // ---- Phase 9: merged zero+scatter stream (unconditional 64 float4/lane)
    {
        float4* Arow4 = (float4*)(A + (size_t)row * NROWS);
        #pragma unroll 4
        for (int ss = 0; ss < 64; ++ss) {
            float4 v = make_float4(0.f, 0.f, 0.f, 0.f);
            #define APPLY_SLOT(kk, ff)                                   \
                if ((kk >> 2) == (unsigned)ss) {                         \
                    int p_ = (int)(kk & 3u);                             \
                    v.x = (p_ == 0) ? ff : v.x;                          \
                    v.y = (p_ == 1) ? ff : v.y;                          \
                    v.z = (p_ == 2) ? ff : v.z;                          \
                    v.w = (p_ == 3) ? ff : v.w;                          \
                }
            APPLY_SLOT(k0, f0)
            APPLY_SLOT(k1, f1)
            APPLY_SLOT(k2, f2)
            APPLY_SLOT(k3, f3)
            #undef APPLY_SLOT
            Arow4[(ss << 5) + j] = v;
        }
    }

    // ---- Phase 10: overflow fixups (>4 distinct keys on a lane): ordered
    //      dword writes, ascending jj = np last-wins ----
    if (ovmask) {
        asm volatile("s_waitcnt vmcnt(0)" ::: "memory");
        unsigned m = ovmask;
        while (m) {
            int jj = __ffs(m) - 1;
            m &= m - 1;
            int c = col_s[r][jj];
            A[(size_t)row * NROWS + c] = cw_s[r][jj].y;
            asm volatile("s_waitcnt vmcnt(0)" ::: "memory");
        }
    }
}

extern "C" void kernel_launch(void* const* d_in, const int* in_sizes, int n_in,
                              void* d_out, int out_size, void* d_ws, size_t ws_size,
                              hipStream_t stream) {
    const float* Y      = (const float*)d_in[0];
    const float* semH   = (const float*)d_in[1];
    const float* orthoH = (const float*)d_in[2];
    const int*   idx    = (const int*)d_in[3];
    const void*  alpha  = d_in[4];
    const void*  beta   = d_in[5];

    float* out  = (float*)d_out;
    float* embs = out;                                   // N*D
    float* A    = out + (size_t)NROWS * DDIM;            // N*N
    float* Yout = A + (size_t)NROWS * NROWS;             // N*D

    school_fused_kernel<<<NROWS / 8, 256, 0, stream>>>(
        Y, semH, orthoH, idx, alpha, beta, embs, A, Yout);
}